// Round 18
// baseline (407.212 us; speedup 1.0000x reference)
//
#include <hip/hip_runtime.h>
#include <hip/hip_bf16.h>

#define GEN_EPS 1e-7f

typedef __attribute__((ext_vector_type(8))) short short8;
typedef __attribute__((ext_vector_type(4))) float f32x4;

// ---------------------------------------------------------------------------
// Fused prep: grid-partitioned {ln_relu (first: streaming bulk), wprep, count}.
// ln_relu: one wave = 4 rows (16 lanes/row, 2xfloat4/lane, 4-step butterfly).
// wprep: granule-linear MFMA frag order:
//   chunk = (c>>4)*(R/32) + (k>>5), 512 shorts; within: [(k&31)>>3][c&15][k&7]
// ---------------------------------------------------------------------------
__global__ void prep_all(
    const float* __restrict__ eW1, const float* __restrict__ eW2,
    const float* __restrict__ nW1, const float* __restrict__ nW2,
    short* __restrict__ eW1P, short* __restrict__ eW2P, short* __restrict__ nW1P,
    short* __restrict__ nW2P,
    const int* __restrict__ e_dst, const int* __restrict__ v_dst,
    int* __restrict__ ce, int* __restrict__ cn, int LE, int En, int nLN,
    const float* __restrict__ ex, const float* __restrict__ vx,
    const float* __restrict__ eg, const float* __restrict__ eb,
    const float* __restrict__ ng, const float* __restrict__ nb_,
    __hip_bfloat16* __restrict__ he, __hip_bfloat16* __restrict__ hn, int E, int N) {
  int b = blockIdx.x;
  int tid = threadIdx.x;

  if (b < nLN) {  // ---- ln_relu role: 4 rows/wave, 16 lanes/row, 32B/lane ----
    int l16 = tid & 15;
    int rr = b * 16 + (tid >> 4);  // 16 rows per 256-thread block
    const float* x;
    const float* g;
    const float* bb;
    __hip_bfloat16* h;
    int r;
    if (rr < E) {
      x = ex; g = eg; bb = eb; h = he; r = rr;
    } else if (rr < E + N) {
      x = vx; g = ng; bb = nb_; h = hn; r = rr - E;
    } else {
      return;
    }
    const float4* xr = (const float4*)(x + (size_t)r * 128);
    float4 va = xr[l16 * 2], vb = xr[l16 * 2 + 1];
    float s = va.x + va.y + va.z + va.w + vb.x + vb.y + vb.z + vb.w;
#pragma unroll
    for (int o = 8; o; o >>= 1) s += __shfl_xor(s, o);
    float m = s * (1.0f / 128.0f);
    float da0 = va.x - m, da1 = va.y - m, da2 = va.z - m, da3 = va.w - m;
    float db0 = vb.x - m, db1 = vb.y - m, db2 = vb.z - m, db3 = vb.w - m;
    float q = da0 * da0 + da1 * da1 + da2 * da2 + da3 * da3 + db0 * db0 + db1 * db1 +
              db2 * db2 + db3 * db3;
#pragma unroll
    for (int o = 8; o; o >>= 1) q += __shfl_xor(q, o);
    float rstd = rsqrtf(q * (1.0f / 128.0f) + 1e-5f);
    float4 ga = ((const float4*)g)[l16 * 2], gb = ((const float4*)g)[l16 * 2 + 1];
    float4 ba = ((const float4*)bb)[l16 * 2], bbv = ((const float4*)bb)[l16 * 2 + 1];
    float2 p01, p23, p45, p67;
    p01.x = fmaxf(fmaf(da0 * rstd, ga.x, ba.x), 0.0f);
    p01.y = fmaxf(fmaf(da1 * rstd, ga.y, ba.y), 0.0f);
    p23.x = fmaxf(fmaf(da2 * rstd, ga.z, ba.z), 0.0f);
    p23.y = fmaxf(fmaf(da3 * rstd, ga.w, ba.w), 0.0f);
    p45.x = fmaxf(fmaf(db0 * rstd, gb.x, bbv.x), 0.0f);
    p45.y = fmaxf(fmaf(db1 * rstd, gb.y, bbv.y), 0.0f);
    p67.x = fmaxf(fmaf(db2 * rstd, gb.z, bbv.z), 0.0f);
    p67.y = fmaxf(fmaf(db3 * rstd, gb.w, bbv.w), 0.0f);
    __hip_bfloat162 q0 = __float22bfloat162_rn(p01);
    __hip_bfloat162 q1 = __float22bfloat162_rn(p23);
    __hip_bfloat162 q2 = __float22bfloat162_rn(p45);
    __hip_bfloat162 q3 = __float22bfloat162_rn(p67);
    uint4 u;
    u.x = *(uint*)&q0;
    u.y = *(uint*)&q1;
    u.z = *(uint*)&q2;
    u.w = *(uint*)&q3;
    ((uint4*)(h + (size_t)r * 128))[l16] = u;
    return;
  }
  b -= nLN;

  if (b < 768) {  // ---- wprep role ----
    const float* W;
    short* WP;
    int R, Cc, c;
    if (b < 256) {
      W = eW1; WP = eW1P; R = 128; Cc = 256; c = b;
    } else if (b < 384) {
      W = eW2; WP = eW2P; R = 256; Cc = 128; c = b - 256;
    } else if (b < 640) {
      W = nW1; WP = nW1P; R = 128; Cc = 256; c = b - 384;
    } else {
      W = nW2; WP = nW2P; R = 256; Cc = 128; c = b - 640;
    }
    size_t tbase = (size_t)(c >> 4) * (size_t)(16 * R);
    int rsub = c & 15;
    for (int k = tid; k < R; k += blockDim.x) {
      __hip_bfloat16 bv = __float2bfloat16(W[(size_t)k * Cc + c]);
      int kk = k & 31;
      WP[tbase + (size_t)(k >> 5) * 512 + (kk >> 3) * 128 + rsub * 8 + (kk & 7)] =
          *(short*)&bv;
    }
    return;
  }
  b -= 768;

  // ---- count role ----
  int i = b * 256 + tid;
  if (i < LE)
    atomicAdd(&ce[e_dst[i]], 1);
  else if (i < LE + En)
    atomicAdd(&cn[v_dst[i - LE]], 1);
}

// ---------------------------------------------------------------------------
// Single-pass exclusive scan (decoupled lookback), both graphs in one launch.
// part[bb]: {status(hi32): 0=empty 1=aggregate 2=inclusive, value(lo32)}.
// part zeroed by the counts memset (carved contiguously).  <=333 blocks, all
// co-resident -> spin-wait is safe.
// ---------------------------------------------------------------------------
__global__ void scan_fused(const int* __restrict__ ce, const int* __restrict__ cn,
                           unsigned long long* __restrict__ part,
                           int* __restrict__ off_e, int* __restrict__ off_n,
                           int* __restrict__ cur_e, int* __restrict__ cur_n,
                           int nbE, int E, int N, int LE, int En) {
  __shared__ int sm[256];
  __shared__ int smPrev;
  int b = blockIdx.x;
  const int* counts;
  int M, nnz, bb;
  int* off;
  int* cursor;
  unsigned long long* pr;
  if (b < nbE) {
    counts = ce; M = E; nnz = LE; bb = b; off = off_e; cursor = cur_e; pr = part;
  } else {
    counts = cn; M = N; nnz = En; bb = b - nbE; off = off_n; cursor = cur_n;
    pr = part + 512;
  }
  int t = threadIdx.x;
  int base = bb * 1024 + t * 4;
  int c[4];
  int s = 0;
#pragma unroll
  for (int i = 0; i < 4; i++) {
    int idx = base + i;
    c[i] = (idx < M) ? counts[idx] : 0;
    s += c[i];
  }
  sm[t] = s;
  __syncthreads();
  for (int o = 1; o < 256; o <<= 1) {
    int v = (t >= o) ? sm[t - o] : 0;
    __syncthreads();
    sm[t] += v;
    __syncthreads();
  }
  int total = sm[255];
  if (t == 0) {
    int prev = 0;
    if (bb == 0) {
      atomicExch(&pr[0], (2ULL << 32) | (unsigned long long)(unsigned)total);
    } else {
      atomicExch(&pr[bb], (1ULL << 32) | (unsigned long long)(unsigned)total);
      int j = bb - 1;
      while (true) {
        unsigned long long v;
        do {
          v = atomicAdd(&pr[j], 0ULL);
        } while ((v >> 32) == 0ULL);
        prev += (int)(v & 0xffffffffULL);
        if ((v >> 32) == 2ULL) break;
        j--;
      }
      atomicExch(&pr[bb], (2ULL << 32) | (unsigned long long)(unsigned)(prev + total));
    }
    smPrev = prev;
  }
  __syncthreads();
  int p = smPrev + sm[t] - s;
#pragma unroll
  for (int i = 0; i < 4; i++) {
    int idx = base + i;
    if (idx < M) {
      off[idx] = p;
      cursor[idx] = p;
      p += c[i];
    }
  }
  if (bb == 0 && t == 0) off[M] = nnz;
}

__global__ void fill_all(const int* __restrict__ e_src, const int* __restrict__ e_dst,
                         const int* __restrict__ v_src, const int* __restrict__ v_dst,
                         int* __restrict__ cur_e, int* __restrict__ cur_n,
                         int* __restrict__ csrs_e, int* __restrict__ csrs_n,
                         int* __restrict__ csre_n, int LE, int En) {
  int i = blockIdx.x * blockDim.x + threadIdx.x;
  if (i < LE) {
    int p = atomicAdd(&cur_e[e_dst[i]], 1);
    csrs_e[p] = e_src[i];
  } else if (i < LE + En) {
    int j = i - LE;
    int p = atomicAdd(&cur_n[v_dst[j]], 1);
    csrs_n[p] = v_src[j];
    csre_n[p] = j;
  }
}

// ---------------------------------------------------------------------------
// Softmax aggregation, one wave per destination row, 2 channels per lane,
// 4-way edge-parallel gathers.  Writes y bf16 PRE-PACKED in MFMA A-frag order.
// ---------------------------------------------------------------------------
template <bool HAS_EATTR>
__global__ __launch_bounds__(256) void aggregate_kernel(
    const __hip_bfloat16* __restrict__ h, const int* __restrict__ off,
    const int* __restrict__ csr_src, const int* __restrict__ csr_eid,
    const ushort* __restrict__ eattr, const float* __restrict__ tptr,
    uint* __restrict__ yP, int M) {
  int lane = threadIdx.x & 63;
  int r = blockIdx.x * 4 + (threadIdx.x >> 6);
  if (r >= M) return;
  const float t = tptr[0];
  float2 hv = __bfloat1622float2(((const __hip_bfloat162*)(h + (size_t)r * 128))[lane]);
  int e0 = off[r], e1 = off[r + 1];
  float d0 = 0.0f, d1 = 0.0f, a0 = 0.0f, a1 = 0.0f;
  for (int e = e0; e < e1; e += 4) {
    int n = e1 - e;
    float2 mv[4];
#pragma unroll
    for (int u = 0; u < 4; u++) {
      int ee = (u < n) ? e + u : e;
      int s = csr_src[ee];
      mv[u] = __bfloat1622float2(((const __hip_bfloat162*)(h + (size_t)s * 128))[lane]);
    }
    if (HAS_EATTR) {
#pragma unroll
      for (int u = 0; u < 4; u++) {
        int ee = (u < n) ? e + u : e;
        int id = csr_eid[ee];
        uint ea = ((const uint*)(eattr + (size_t)id * 128))[lane];
        float2 ef = __bfloat1622float2(*(__hip_bfloat162*)&ea);
        mv[u].x += ef.x;
        mv[u].y += ef.y;
      }
    }
#pragma unroll
    for (int u = 0; u < 4; u++) {
      float w = (u < n) ? 1.0f : 0.0f;
      float m0 = fmaxf(mv[u].x, 0.0f) + GEN_EPS;
      float m1 = fmaxf(mv[u].y, 0.0f) + GEN_EPS;
      float al0 = __expf(m0 * t) * w, al1 = __expf(m1 * t) * w;
      d0 += al0;
      d1 += al1;
      a0 = fmaf(al0, m0, a0);
      a1 = fmaf(al1, m1, a1);
    }
  }
  float2 yv;
  yv.x = (e1 > e0 ? a0 / d0 : 0.0f) + hv.x;
  yv.y = (e1 > e0 ? a1 / d1 : 0.0f) + hv.y;
  __hip_bfloat162 yb2 = __float22bfloat162_rn(yv);
  yP[(r >> 4) * 1024 + (lane >> 4) * 256 + (r & 15) * 16 + (lane & 15)] = *(uint*)&yb2;
}

// ---------------------------------------------------------------------------
// Persistent MLP (512 threads, 8 waves, 2 waves/SIMD; x loaded mid-iteration,
// single-buffered).  W1+W2 in LDS (granule-linear -> conflict-free b128);
// waves independent, no barriers in loop.
// ---------------------------------------------------------------------------
template <bool WRITE_BF16>
__global__ __launch_bounds__(512, 2) void mlp_kernel(
    const float* __restrict__ x, const short* yP, const short* __restrict__ W1P,
    const float* __restrict__ b1, const float* __restrict__ lng,
    const float* __restrict__ lnb, const short* __restrict__ W2P,
    const float* __restrict__ b2, float* __restrict__ out, ushort* out16,
    int ntiles, int stride, int M) {
  __shared__ short W1s[128 * 256];
  __shared__ short W2s[256 * 128];
  __shared__ short scr[8][2][16 * 34];

  const int tid = threadIdx.x, lane = tid & 63, wv = tid >> 6;
  const int rA = lane & 15, hi = lane >> 4;
  const int kA = hi * 8, jrow = hi * 4;
  const int foW = lane * 8;
  const int foA = rA * 32 + kA;

  {
    const short8* g1 = (const short8*)W1P;
    short8* l1 = (short8*)W1s;
#pragma unroll
    for (int i = 0; i < 8; i++) l1[i * 512 + tid] = g1[i * 512 + tid];
    const short8* g2 = (const short8*)W2P;
    short8* l2 = (short8*)W2s;
#pragma unroll
    for (int i = 0; i < 8; i++) l2[i * 512 + tid] = g2[i * 512 + tid];
  }

  float b1v[16], lngv[16], lnbv[16], b2v[8];
#pragma unroll
  for (int ct = 0; ct < 16; ct++) {
    int col = ct * 16 + rA;
    b1v[ct] = b1[col];
    lngv[ct] = lng[col];
    lnbv[ct] = lnb[col];
  }
#pragma unroll
  for (int ct = 0; ct < 8; ct++) b2v[ct] = b2[ct * 16 + rA];

  __syncthreads();

  int t = blockIdx.x * 8 + wv;
  short8 yA0, yA1, yA2, yA3;
  if (t < ntiles) {
    const short* yb = yP + (size_t)t * 2048 + foA;
    yA0 = *(const short8*)(yb);
    yA1 = *(const short8*)(yb + 512);
    yA2 = *(const short8*)(yb + 1024);
    yA3 = *(const short8*)(yb + 1536);
  }

  for (; t < ntiles; t += stride) {
    const int row0 = t * 16;

    f32x4 C1[16];
#pragma unroll
    for (int i = 0; i < 16; i++) C1[i] = (f32x4)0.0f;
#pragma unroll
    for (int kc = 0; kc < 4; kc++) {
      short8 a = (kc == 0) ? yA0 : (kc == 1) ? yA1 : (kc == 2) ? yA2 : yA3;
#pragma unroll
      for (int ct = 0; ct < 16; ct++) {
        short8 B = *(const short8*)&W1s[(ct * 4 + kc) * 512 + foW];
        C1[ct] = __builtin_amdgcn_mfma_f32_16x16x32_bf16(a, B, C1[ct], 0, 0, 0);
      }
    }

    {
      int tn = t + stride;
      int tc = (tn < ntiles) ? tn : t;
      const short* yb = yP + (size_t)tc * 2048 + foA;
      yA0 = *(const short8*)(yb);
      yA1 = *(const short8*)(yb + 512);
      yA2 = *(const short8*)(yb + 1024);
      yA3 = *(const short8*)(yb + 1536);
    }

    float xv[32];
#pragma unroll
    for (int ct = 0; ct < 8; ct++)
#pragma unroll
      for (int j = 0; j < 4; j++) {
        int row = row0 + jrow + j;
        int rr = (row < M) ? row : (M - 1);
        xv[ct * 4 + j] = x[(size_t)rr * 128 + ct * 16 + rA];
      }

#pragma unroll
    for (int ct = 0; ct < 16; ct++)
#pragma unroll
      for (int j = 0; j < 4; j++) C1[ct][j] += b1v[ct];

    float mean[4], rstd[4];
#pragma unroll
    for (int j = 0; j < 4; j++) {
      float p = 0.0f, q = 0.0f;
#pragma unroll
      for (int ct = 0; ct < 16; ct++) {
        p += C1[ct][j];
        q = fmaf(C1[ct][j], C1[ct][j], q);
      }
#pragma unroll
      for (int o = 1; o < 16; o <<= 1) {
        p += __shfl_xor(p, o);
        q += __shfl_xor(q, o);
      }
      float m = p * (1.0f / 256.0f);
      mean[j] = m;
      rstd[j] = rsqrtf(q * (1.0f / 256.0f) - m * m + 1e-5f);
    }

    f32x4 C2[8];
#pragma unroll
    for (int i = 0; i < 8; i++) C2[i] = (f32x4)0.0f;
#pragma unroll
    for (int kc = 0; kc < 8; kc++) {
      short* s = &scr[wv][kc & 1][0];
#pragma unroll
      for (int ct2 = 0; ct2 < 2; ct2++) {
        int ctg = kc * 2 + ct2;
#pragma unroll
        for (int j = 0; j < 4; j++) {
          float v =
              fmaxf(fmaf((C1[ctg][j] - mean[j]) * rstd[j], lngv[ctg], lnbv[ctg]), 0.0f);
          __hip_bfloat16 bv = __float2bfloat16(v);
          s[(jrow + j) * 34 + ct2 * 16 + rA] = *(short*)&bv;
        }
      }
      asm volatile("s_waitcnt lgkmcnt(0)" ::: "memory");
      __builtin_amdgcn_sched_barrier(0);
      short8 a = *(const short8*)&s[rA * 34 + kA];
#pragma unroll
      for (int ct = 0; ct < 8; ct++) {
        short8 B = *(const short8*)&W2s[(ct * 8 + kc) * 512 + foW];
        C2[ct] = __builtin_amdgcn_mfma_f32_16x16x32_bf16(a, B, C2[ct], 0, 0, 0);
      }
    }

#pragma unroll
    for (int ct = 0; ct < 8; ct++) {
#pragma unroll
      for (int j = 0; j < 4; j++) {
        int row = row0 + jrow + j;
        if (row < M) {
          size_t idx = (size_t)row * 128 + ct * 16 + rA;
          float o = C2[ct][j] + b2v[ct] + xv[ct * 4 + j];
          out[idx] = o;
          if (WRITE_BF16) {
            __hip_bfloat16 bo = __float2bfloat16(o);
            out16[idx] = *(ushort*)&bo;
          }
        }
      }
    }
  }
}

// ---------------------------------------------------------------------------
extern "C" void kernel_launch(void* const* d_in, const int* in_sizes, int n_in,
                              void* d_out, int out_size, void* d_ws, size_t ws_size,
                              hipStream_t stream) {
  const int C = 128;
  const float* v_x = (const float*)d_in[0];
  const float* e_x = (const float*)d_in[1];
  const int* v_ei = (const int*)d_in[2];
  const int* e_ei = (const int*)d_in[3];
  const int N = in_sizes[0] / C;
  const int E = in_sizes[1] / C;
  const int LE = in_sizes[3] / 2;

  const float* ep[9];
  const float* np_[9];
  for (int i = 0; i < 9; i++) ep[i] = (const float*)d_in[4 + i];
  for (int i = 0; i < 9; i++) np_[i] = (const float*)d_in[13 + i];

  float* v_out = (float*)d_out;
  float* e_out = (float*)d_out + (size_t)N * C;

  char* wsp = (char*)d_ws;
  size_t o = 0;
  auto carve = [&](size_t bytes) {
    void* p = wsp + o;
    o += (bytes + 255) & ~(size_t)255;
    return p;
  };
  short* yPe = (short*)carve((size_t)E * C * 2);  // edge packed y; later bf16 e_out
  short* yPn = (short*)carve((size_t)N * C * 2);  // node packed y
  int* counts = (int*)carve((size_t)(E + N) * 4);
  unsigned long long* part = (unsigned long long*)carve(1024 * 8);  // after counts
  int* off_e = (int*)carve(((size_t)E + 1) * 4);
  int* off_n = (int*)carve(((size_t)N + 1) * 4);
  int* cur_e = (int*)carve((size_t)E * 4);
  int* cur_n = (int*)carve((size_t)N * 4);
  int* csrs_e = (int*)carve((size_t)LE * 4);
  int* csrs_n = (int*)carve((size_t)E * 4);
  int* csre_n = (int*)carve((size_t)E * 4);
  short* eW1P = (short*)carve((size_t)256 * 128 * 2);
  short* eW2P = (short*)carve((size_t)128 * 256 * 2);
  short* nW1P = (short*)carve((size_t)256 * 128 * 2);
  short* nW2P = (short*)carve((size_t)128 * 256 * 2);
  (void)ws_size;
  (void)n_in;
  (void)out_size;

  int* counts_e = counts;
  int* counts_n = counts + E;
  __hip_bfloat16* h_e = (__hip_bfloat16*)e_out;  // dead before mlp_e writes
  __hip_bfloat16* h_n = (__hip_bfloat16*)v_out;  // dead before mlp_n writes

  // ---- fused prep: ln_relu + wprep + count; memset covers counts AND part ----
  size_t counts_pad = (((size_t)(E + N) * 4) + 255) & ~(size_t)255;
  hipMemsetAsync(counts, 0, counts_pad + 1024 * 8, stream);
  int nLN = (E + N + 15) / 16;
  int nCNT = (LE + E + 255) / 256;
  prep_all<<<nLN + 768 + nCNT, 256, 0, stream>>>(
      ep[3], ep[7], np_[3], np_[7], eW1P, eW2P, nW1P, nW2P, e_ei + LE, v_ei + E,
      counts_e, counts_n, LE, E, nLN, e_x, v_x, ep[0], ep[1], np_[0], np_[1], h_e, h_n,
      E, N);
  int nbE = (E + 1023) / 1024, nbN = (N + 1023) / 1024;
  scan_fused<<<nbE + nbN, 256, 0, stream>>>(counts_e, counts_n, part, off_e, off_n,
                                            cur_e, cur_n, nbE, E, N, LE, E);
  fill_all<<<(LE + E + 255) / 256, 256, 0, stream>>>(e_ei, e_ei + LE, v_ei, v_ei + E,
                                                     cur_e, cur_n, csrs_e, csrs_n, csre_n,
                                                     LE, E);

  // ---- edge layer ----
  aggregate_kernel<false><<<(E + 3) / 4, 256, 0, stream>>>(h_e, off_e, csrs_e, nullptr,
                                                           nullptr, ep[2], (uint*)yPe, E);
  {
    int ntiles = (E + 15) / 16;
    int gblocks = (ntiles + 7) / 8;
    if (gblocks > 256) gblocks = 256;
    int stride = gblocks * 8;
    mlp_kernel<true><<<gblocks, 512, 0, stream>>>(e_x, yPe, eW1P, ep[4], ep[5], ep[6],
                                                  eW2P, ep[8], e_out, (ushort*)yPe,
                                                  ntiles, stride, E);
  }

  // ---- node layer ----
  aggregate_kernel<true><<<(N + 3) / 4, 256, 0, stream>>>(h_n, off_n, csrs_n, csre_n,
                                                          (const ushort*)yPe, np_[2],
                                                          (uint*)yPn, N);
  {
    int ntiles = (N + 15) / 16;
    int gblocks = (ntiles + 7) / 8;
    if (gblocks > 256) gblocks = 256;
    int stride = gblocks * 8;
    mlp_kernel<false><<<gblocks, 512, 0, stream>>>(v_x, yPn, nW1P, np_[4], np_[5], np_[6],
                                                   nW2P, np_[8], v_out, nullptr, ntiles,
                                                   stride, N);
  }
}

// Round 19
// 401.458 us; speedup vs baseline: 1.0143x; 1.0143x over previous
//
#include <hip/hip_runtime.h>
#include <hip/hip_bf16.h>

#define GEN_EPS 1e-7f

typedef __attribute__((ext_vector_type(8))) short short8;
typedef __attribute__((ext_vector_type(4))) float f32x4;

// ---------------------------------------------------------------------------
// Fused prep: grid-partitioned {wprep(768 blk), count, ln_relu}.
// ln_relu: one wave = 2 rows (32 lanes/row, float4/lane, 5-step butterfly).
// wprep: granule-linear MFMA frag order:
//   chunk = (c>>4)*(R/32) + (k>>5), 512 shorts; within: [(k&31)>>3][c&15][k&7]
// ---------------------------------------------------------------------------
__global__ void prep_all(
    const float* __restrict__ eW1, const float* __restrict__ eW2,
    const float* __restrict__ nW1, const float* __restrict__ nW2,
    short* __restrict__ eW1P, short* __restrict__ eW2P, short* __restrict__ nW1P,
    short* __restrict__ nW2P,
    const int* __restrict__ e_dst, const int* __restrict__ v_dst,
    int* __restrict__ ce, int* __restrict__ cn, int LE, int En, int nCNT,
    const float* __restrict__ ex, const float* __restrict__ vx,
    const float* __restrict__ eg, const float* __restrict__ eb,
    const float* __restrict__ ng, const float* __restrict__ nb_,
    __hip_bfloat16* __restrict__ he, __hip_bfloat16* __restrict__ hn, int E, int N) {
  int b = blockIdx.x;
  int tid = threadIdx.x;

  if (b < 768) {  // ---- wprep role ----
    const float* W;
    short* WP;
    int R, Cc, c;
    if (b < 256) {
      W = eW1; WP = eW1P; R = 128; Cc = 256; c = b;
    } else if (b < 384) {
      W = eW2; WP = eW2P; R = 256; Cc = 128; c = b - 256;
    } else if (b < 640) {
      W = nW1; WP = nW1P; R = 128; Cc = 256; c = b - 384;
    } else {
      W = nW2; WP = nW2P; R = 256; Cc = 128; c = b - 640;
    }
    size_t tbase = (size_t)(c >> 4) * (size_t)(16 * R);
    int rsub = c & 15;
    for (int k = tid; k < R; k += blockDim.x) {
      __hip_bfloat16 bv = __float2bfloat16(W[(size_t)k * Cc + c]);
      int kk = k & 31;
      WP[tbase + (size_t)(k >> 5) * 512 + (kk >> 3) * 128 + rsub * 8 + (kk & 7)] =
          *(short*)&bv;
    }
    return;
  }
  b -= 768;

  if (b < nCNT) {  // ---- count role ----
    int i = b * 256 + tid;
    if (i < LE)
      atomicAdd(&ce[e_dst[i]], 1);
    else if (i < LE + En)
      atomicAdd(&cn[v_dst[i - LE]], 1);
    return;
  }
  b -= nCNT;

  // ---- ln_relu role: 2 rows per wave, float4 per lane ----
  int l32 = tid & 31;
  int rr = b * 8 + ((tid & 255) >> 5);  // 8 rows per 256-thread block
  const float* x;
  const float* g;
  const float* bb;
  __hip_bfloat16* h;
  int r;
  if (rr < E) {
    x = ex; g = eg; bb = eb; h = he; r = rr;
  } else if (rr < E + N) {
    x = vx; g = ng; bb = nb_; h = hn; r = rr - E;
  } else {
    return;
  }
  float4 v = ((const float4*)(x + (size_t)r * 128))[l32];
  float s = v.x + v.y + v.z + v.w;
#pragma unroll
  for (int o = 16; o; o >>= 1) s += __shfl_xor(s, o);
  float m = s * (1.0f / 128.0f);
  float d0 = v.x - m, d1 = v.y - m, d2 = v.z - m, d3 = v.w - m;
  float q = d0 * d0 + d1 * d1 + d2 * d2 + d3 * d3;
#pragma unroll
  for (int o = 16; o; o >>= 1) q += __shfl_xor(q, o);
  float rstd = rsqrtf(q * (1.0f / 128.0f) + 1e-5f);
  float4 gv = ((const float4*)g)[l32];
  float4 bv = ((const float4*)bb)[l32];
  float2 h01, h23;
  h01.x = fmaxf(fmaf(d0 * rstd, gv.x, bv.x), 0.0f);
  h01.y = fmaxf(fmaf(d1 * rstd, gv.y, bv.y), 0.0f);
  h23.x = fmaxf(fmaf(d2 * rstd, gv.z, bv.z), 0.0f);
  h23.y = fmaxf(fmaf(d3 * rstd, gv.w, bv.w), 0.0f);
  __hip_bfloat162 p0 = __float22bfloat162_rn(h01);
  __hip_bfloat162 p1 = __float22bfloat162_rn(h23);
  uint2 u;
  u.x = *(uint*)&p0;
  u.y = *(uint*)&p1;
  ((uint2*)(h + (size_t)r * 128))[l32] = u;
}

// ---------------------------------------------------------------------------
// Single-pass exclusive scan (decoupled lookback), both graphs in one launch.
// ---------------------------------------------------------------------------
__global__ void scan_fused(const int* __restrict__ ce, const int* __restrict__ cn,
                           unsigned long long* __restrict__ part,
                           int* __restrict__ off_e, int* __restrict__ off_n,
                           int* __restrict__ cur_e, int* __restrict__ cur_n,
                           int nbE, int E, int N, int LE, int En) {
  __shared__ int sm[256];
  __shared__ int smPrev;
  int b = blockIdx.x;
  const int* counts;
  int M, nnz, bb;
  int* off;
  int* cursor;
  unsigned long long* pr;
  if (b < nbE) {
    counts = ce; M = E; nnz = LE; bb = b; off = off_e; cursor = cur_e; pr = part;
  } else {
    counts = cn; M = N; nnz = En; bb = b - nbE; off = off_n; cursor = cur_n;
    pr = part + 512;
  }
  int t = threadIdx.x;
  int base = bb * 1024 + t * 4;
  int c[4];
  int s = 0;
#pragma unroll
  for (int i = 0; i < 4; i++) {
    int idx = base + i;
    c[i] = (idx < M) ? counts[idx] : 0;
    s += c[i];
  }
  sm[t] = s;
  __syncthreads();
  for (int o = 1; o < 256; o <<= 1) {
    int v = (t >= o) ? sm[t - o] : 0;
    __syncthreads();
    sm[t] += v;
    __syncthreads();
  }
  int total = sm[255];
  if (t == 0) {
    int prev = 0;
    if (bb == 0) {
      atomicExch(&pr[0], (2ULL << 32) | (unsigned long long)(unsigned)total);
    } else {
      atomicExch(&pr[bb], (1ULL << 32) | (unsigned long long)(unsigned)total);
      int j = bb - 1;
      while (true) {
        unsigned long long v;
        do {
          v = atomicAdd(&pr[j], 0ULL);
        } while ((v >> 32) == 0ULL);
        prev += (int)(v & 0xffffffffULL);
        if ((v >> 32) == 2ULL) break;
        j--;
      }
      atomicExch(&pr[bb], (2ULL << 32) | (unsigned long long)(unsigned)(prev + total));
    }
    smPrev = prev;
  }
  __syncthreads();
  int p = smPrev + sm[t] - s;
#pragma unroll
  for (int i = 0; i < 4; i++) {
    int idx = base + i;
    if (idx < M) {
      off[idx] = p;
      cursor[idx] = p;
      p += c[i];
    }
  }
  if (bb == 0 && t == 0) off[M] = nnz;
}

// ---------------------------------------------------------------------------
// Fill: edge graph -> csrs_e (src only); node graph -> interleaved int2
// {src, eid} (one 8B scattered store instead of two 4B).
// ---------------------------------------------------------------------------
__global__ void fill_all(const int* __restrict__ e_src, const int* __restrict__ e_dst,
                         const int* __restrict__ v_src, const int* __restrict__ v_dst,
                         int* __restrict__ cur_e, int* __restrict__ cur_n,
                         int* __restrict__ csrs_e, int2* __restrict__ csrn2,
                         int LE, int En) {
  int i = blockIdx.x * blockDim.x + threadIdx.x;
  if (i < LE) {
    int p = atomicAdd(&cur_e[e_dst[i]], 1);
    csrs_e[p] = e_src[i];
  } else if (i < LE + En) {
    int j = i - LE;
    int p = atomicAdd(&cur_n[v_dst[j]], 1);
    int2 st;
    st.x = v_src[j];
    st.y = j;
    csrn2[p] = st;
  }
}

// ---------------------------------------------------------------------------
// Softmax aggregation: one wave = 2 rows (32 lanes/row, 4 channels/lane via
// 8B gathers), 4-way edge-parallel unroll -> up to 8 independent gather
// streams per wave.  HAS_EATTR path reads interleaved int2 {src,eid}.
// Writes y bf16 PRE-PACKED in MFMA A-frag order (pair index c at
// (r>>4)*1024 + (c>>4)*256 + (r&15)*16 + (c&15)).
// ---------------------------------------------------------------------------
template <bool HAS_EATTR>
__global__ __launch_bounds__(256) void aggregate_kernel(
    const __hip_bfloat16* __restrict__ h, const int* __restrict__ off,
    const int* __restrict__ csr_src, const int2* __restrict__ csr2,
    const ushort* __restrict__ eattr, const float* __restrict__ tptr,
    uint* __restrict__ yP, int M) {
  int l32 = threadIdx.x & 31;
  int r = blockIdx.x * 8 + (threadIdx.x >> 5);
  if (r >= M) return;
  const float t = tptr[0];
  int e0 = off[r], e1 = off[r + 1];
  float d0 = 0, d1 = 0, d2 = 0, d3 = 0, a0 = 0, a1 = 0, a2 = 0, a3 = 0;
  for (int e = e0; e < e1; e += 4) {
    int n = e1 - e;
    uint2 mraw[4];
    int ids[4];
#pragma unroll
    for (int u = 0; u < 4; u++) {
      int ee = (u < n) ? e + u : e;
      int s;
      if (HAS_EATTR) {
        int2 se = csr2[ee];
        s = se.x;
        ids[u] = se.y;
      } else {
        s = csr_src[ee];
      }
      mraw[u] = ((const uint2*)(h + (size_t)s * 128))[l32];
    }
#pragma unroll
    for (int u = 0; u < 4; u++) {
      float2 lo = __bfloat1622float2(*(__hip_bfloat162*)&mraw[u].x);
      float2 hi2 = __bfloat1622float2(*(__hip_bfloat162*)&mraw[u].y);
      if (HAS_EATTR) {
        uint2 er = ((const uint2*)(eattr + (size_t)ids[u] * 128))[l32];
        float2 el = __bfloat1622float2(*(__hip_bfloat162*)&er.x);
        float2 eh = __bfloat1622float2(*(__hip_bfloat162*)&er.y);
        lo.x += el.x;
        lo.y += el.y;
        hi2.x += eh.x;
        hi2.y += eh.y;
      }
      float w = (u < n) ? 1.0f : 0.0f;
      float m0 = fmaxf(lo.x, 0.0f) + GEN_EPS;
      float m1 = fmaxf(lo.y, 0.0f) + GEN_EPS;
      float m2 = fmaxf(hi2.x, 0.0f) + GEN_EPS;
      float m3 = fmaxf(hi2.y, 0.0f) + GEN_EPS;
      float al0 = __expf(m0 * t) * w, al1 = __expf(m1 * t) * w;
      float al2 = __expf(m2 * t) * w, al3 = __expf(m3 * t) * w;
      d0 += al0;
      d1 += al1;
      d2 += al2;
      d3 += al3;
      a0 = fmaf(al0, m0, a0);
      a1 = fmaf(al1, m1, a1);
      a2 = fmaf(al2, m2, a2);
      a3 = fmaf(al3, m3, a3);
    }
  }
  uint2 hraw = ((const uint2*)(h + (size_t)r * 128))[l32];
  float2 hlo = __bfloat1622float2(*(__hip_bfloat162*)&hraw.x);
  float2 hhi = __bfloat1622float2(*(__hip_bfloat162*)&hraw.y);
  bool has = e1 > e0;
  float2 y01, y23;
  y01.x = (has ? a0 / d0 : 0.0f) + hlo.x;
  y01.y = (has ? a1 / d1 : 0.0f) + hlo.y;
  y23.x = (has ? a2 / d2 : 0.0f) + hhi.x;
  y23.y = (has ? a3 / d3 : 0.0f) + hhi.y;
  __hip_bfloat162 pb0 = __float22bfloat162_rn(y01);
  __hip_bfloat162 pb1 = __float22bfloat162_rn(y23);
  int base = (r >> 4) * 1024 + (r & 15) * 16;
  int c0 = 2 * l32, c1 = 2 * l32 + 1;
  yP[base + (c0 >> 4) * 256 + (c0 & 15)] = *(uint*)&pb0;
  yP[base + (c1 >> 4) * 256 + (c1 & 15)] = *(uint*)&pb1;
}

// ---------------------------------------------------------------------------
// Persistent MLP (512 threads, 8 waves, 2 waves/SIMD; x loaded mid-iteration,
// single-buffered).  W1+W2 in LDS (granule-linear -> conflict-free b128);
// waves independent, no barriers in loop.
// ---------------------------------------------------------------------------
template <bool WRITE_BF16>
__global__ __launch_bounds__(512, 2) void mlp_kernel(
    const float* __restrict__ x, const short* yP, const short* __restrict__ W1P,
    const float* __restrict__ b1, const float* __restrict__ lng,
    const float* __restrict__ lnb, const short* __restrict__ W2P,
    const float* __restrict__ b2, float* __restrict__ out, ushort* out16,
    int ntiles, int stride, int M) {
  __shared__ short W1s[128 * 256];
  __shared__ short W2s[256 * 128];
  __shared__ short scr[8][2][16 * 34];

  const int tid = threadIdx.x, lane = tid & 63, wv = tid >> 6;
  const int rA = lane & 15, hi = lane >> 4;
  const int kA = hi * 8, jrow = hi * 4;
  const int foW = lane * 8;
  const int foA = rA * 32 + kA;

  {
    const short8* g1 = (const short8*)W1P;
    short8* l1 = (short8*)W1s;
#pragma unroll
    for (int i = 0; i < 8; i++) l1[i * 512 + tid] = g1[i * 512 + tid];
    const short8* g2 = (const short8*)W2P;
    short8* l2 = (short8*)W2s;
#pragma unroll
    for (int i = 0; i < 8; i++) l2[i * 512 + tid] = g2[i * 512 + tid];
  }

  float b1v[16], lngv[16], lnbv[16], b2v[8];
#pragma unroll
  for (int ct = 0; ct < 16; ct++) {
    int col = ct * 16 + rA;
    b1v[ct] = b1[col];
    lngv[ct] = lng[col];
    lnbv[ct] = lnb[col];
  }
#pragma unroll
  for (int ct = 0; ct < 8; ct++) b2v[ct] = b2[ct * 16 + rA];

  __syncthreads();

  int t = blockIdx.x * 8 + wv;
  short8 yA0, yA1, yA2, yA3;
  if (t < ntiles) {
    const short* yb = yP + (size_t)t * 2048 + foA;
    yA0 = *(const short8*)(yb);
    yA1 = *(const short8*)(yb + 512);
    yA2 = *(const short8*)(yb + 1024);
    yA3 = *(const short8*)(yb + 1536);
  }

  for (; t < ntiles; t += stride) {
    const int row0 = t * 16;

    f32x4 C1[16];
#pragma unroll
    for (int i = 0; i < 16; i++) C1[i] = (f32x4)0.0f;
#pragma unroll
    for (int kc = 0; kc < 4; kc++) {
      short8 a = (kc == 0) ? yA0 : (kc == 1) ? yA1 : (kc == 2) ? yA2 : yA3;
#pragma unroll
      for (int ct = 0; ct < 16; ct++) {
        short8 B = *(const short8*)&W1s[(ct * 4 + kc) * 512 + foW];
        C1[ct] = __builtin_amdgcn_mfma_f32_16x16x32_bf16(a, B, C1[ct], 0, 0, 0);
      }
    }

    {
      int tn = t + stride;
      int tc = (tn < ntiles) ? tn : t;
      const short* yb = yP + (size_t)tc * 2048 + foA;
      yA0 = *(const short8*)(yb);
      yA1 = *(const short8*)(yb + 512);
      yA2 = *(const short8*)(yb + 1024);
      yA3 = *(const short8*)(yb + 1536);
    }

    float xv[32];
#pragma unroll
    for (int ct = 0; ct < 8; ct++)
#pragma unroll
      for (int j = 0; j < 4; j++) {
        int row = row0 + jrow + j;
        int rr = (row < M) ? row : (M - 1);
        xv[ct * 4 + j] = x[(size_t)rr * 128 + ct * 16 + rA];
      }

#pragma unroll
    for (int ct = 0; ct < 16; ct++)
#pragma unroll
      for (int j = 0; j < 4; j++) C1[ct][j] += b1v[ct];

    float mean[4], rstd[4];
#pragma unroll
    for (int j = 0; j < 4; j++) {
      float p = 0.0f, q = 0.0f;
#pragma unroll
      for (int ct = 0; ct < 16; ct++) {
        p += C1[ct][j];
        q = fmaf(C1[ct][j], C1[ct][j], q);
      }
#pragma unroll
      for (int o = 1; o < 16; o <<= 1) {
        p += __shfl_xor(p, o);
        q += __shfl_xor(q, o);
      }
      float m = p * (1.0f / 256.0f);
      mean[j] = m;
      rstd[j] = rsqrtf(q * (1.0f / 256.0f) - m * m + 1e-5f);
    }

    f32x4 C2[8];
#pragma unroll
    for (int i = 0; i < 8; i++) C2[i] = (f32x4)0.0f;
#pragma unroll
    for (int kc = 0; kc < 8; kc++) {
      short* s = &scr[wv][kc & 1][0];
#pragma unroll
      for (int ct2 = 0; ct2 < 2; ct2++) {
        int ctg = kc * 2 + ct2;
#pragma unroll
        for (int j = 0; j < 4; j++) {
          float v =
              fmaxf(fmaf((C1[ctg][j] - mean[j]) * rstd[j], lngv[ctg], lnbv[ctg]), 0.0f);
          __hip_bfloat16 bv = __float2bfloat16(v);
          s[(jrow + j) * 34 + ct2 * 16 + rA] = *(short*)&bv;
        }
      }
      asm volatile("s_waitcnt lgkmcnt(0)" ::: "memory");
      __builtin_amdgcn_sched_barrier(0);
      short8 a = *(const short8*)&s[rA * 34 + kA];
#pragma unroll
      for (int ct = 0; ct < 8; ct++) {
        short8 B = *(const short8*)&W2s[(ct * 8 + kc) * 512 + foW];
        C2[ct] = __builtin_amdgcn_mfma_f32_16x16x32_bf16(a, B, C2[ct], 0, 0, 0);
      }
    }

#pragma unroll
    for (int ct = 0; ct < 8; ct++) {
#pragma unroll
      for (int j = 0; j < 4; j++) {
        int row = row0 + jrow + j;
        if (row < M) {
          size_t idx = (size_t)row * 128 + ct * 16 + rA;
          float o = C2[ct][j] + b2v[ct] + xv[ct * 4 + j];
          out[idx] = o;
          if (WRITE_BF16) {
            __hip_bfloat16 bo = __float2bfloat16(o);
            out16[idx] = *(ushort*)&bo;
          }
        }
      }
    }
  }
}

// ---------------------------------------------------------------------------
extern "C" void kernel_launch(void* const* d_in, const int* in_sizes, int n_in,
                              void* d_out, int out_size, void* d_ws, size_t ws_size,
                              hipStream_t stream) {
  const int C = 128;
  const float* v_x = (const float*)d_in[0];
  const float* e_x = (const float*)d_in[1];
  const int* v_ei = (const int*)d_in[2];
  const int* e_ei = (const int*)d_in[3];
  const int N = in_sizes[0] / C;
  const int E = in_sizes[1] / C;
  const int LE = in_sizes[3] / 2;

  const float* ep[9];
  const float* np_[9];
  for (int i = 0; i < 9; i++) ep[i] = (const float*)d_in[4 + i];
  for (int i = 0; i < 9; i++) np_[i] = (const float*)d_in[13 + i];

  float* v_out = (float*)d_out;
  float* e_out = (float*)d_out + (size_t)N * C;

  char* wsp = (char*)d_ws;
  size_t o = 0;
  auto carve = [&](size_t bytes) {
    void* p = wsp + o;
    o += (bytes + 255) & ~(size_t)255;
    return p;
  };
  short* yPe = (short*)carve((size_t)E * C * 2);  // edge packed y; later bf16 e_out
  short* yPn = (short*)carve((size_t)N * C * 2);  // node packed y
  int* counts = (int*)carve((size_t)(E + N) * 4);
  unsigned long long* part = (unsigned long long*)carve(1024 * 8);  // after counts
  int* off_e = (int*)carve(((size_t)E + 1) * 4);
  int* off_n = (int*)carve(((size_t)N + 1) * 4);
  int* cur_e = (int*)carve((size_t)E * 4);
  int* cur_n = (int*)carve((size_t)N * 4);
  int* csrs_e = (int*)carve((size_t)LE * 4);
  int2* csrn2 = (int2*)carve((size_t)E * 8);
  short* eW1P = (short*)carve((size_t)256 * 128 * 2);
  short* eW2P = (short*)carve((size_t)128 * 256 * 2);
  short* nW1P = (short*)carve((size_t)256 * 128 * 2);
  short* nW2P = (short*)carve((size_t)128 * 256 * 2);
  (void)ws_size;
  (void)n_in;
  (void)out_size;

  int* counts_e = counts;
  int* counts_n = counts + E;
  __hip_bfloat16* h_e = (__hip_bfloat16*)e_out;  // dead before mlp_e writes
  __hip_bfloat16* h_n = (__hip_bfloat16*)v_out;  // dead before mlp_n writes

  // ---- fused prep: wprep + count + ln_relu; memset covers counts AND part ----
  size_t counts_pad = (((size_t)(E + N) * 4) + 255) & ~(size_t)255;
  hipMemsetAsync(counts, 0, counts_pad + 1024 * 8, stream);
  int nCNT = (LE + E + 255) / 256;
  int nLN = (E + N + 7) / 8;
  prep_all<<<768 + nCNT + nLN, 256, 0, stream>>>(
      ep[3], ep[7], np_[3], np_[7], eW1P, eW2P, nW1P, nW2P, e_ei + LE, v_ei + E,
      counts_e, counts_n, LE, E, nCNT, e_x, v_x, ep[0], ep[1], np_[0], np_[1], h_e, h_n,
      E, N);
  int nbE = (E + 1023) / 1024, nbN = (N + 1023) / 1024;
  scan_fused<<<nbE + nbN, 256, 0, stream>>>(counts_e, counts_n, part, off_e, off_n,
                                            cur_e, cur_n, nbE, E, N, LE, E);
  fill_all<<<(LE + E + 255) / 256, 256, 0, stream>>>(e_ei, e_ei + LE, v_ei, v_ei + E,
                                                     cur_e, cur_n, csrs_e, csrn2, LE, E);

  // ---- edge layer ----
  aggregate_kernel<false><<<(E + 7) / 8, 256, 0, stream>>>(
      h_e, off_e, csrs_e, nullptr, nullptr, ep[2], (uint*)yPe, E);
  {
    int ntiles = (E + 15) / 16;
    int gblocks = (ntiles + 7) / 8;
    if (gblocks > 256) gblocks = 256;
    int stride = gblocks * 8;
    mlp_kernel<true><<<gblocks, 512, 0, stream>>>(e_x, yPe, eW1P, ep[4], ep[5], ep[6],
                                                  eW2P, ep[8], e_out, (ushort*)yPe,
                                                  ntiles, stride, E);
  }

  // ---- node layer ----
  aggregate_kernel<true><<<(N + 7) / 8, 256, 0, stream>>>(
      h_n, off_n, nullptr, csrn2, (const ushort*)yPe, np_[2], (uint*)yPn, N);
  {
    int ntiles = (N + 15) / 16;
    int gblocks = (ntiles + 7) / 8;
    if (gblocks > 256) gblocks = 256;
    int stride = gblocks * 8;
    mlp_kernel<false><<<gblocks, 512, 0, stream>>>(v_x, yPn, nW1P, np_[4], np_[5], np_[6],
                                                   nW2P, np_[8], v_out, nullptr, ntiles,
                                                   stride, N);
  }
}

// Round 20
// 397.372 us; speedup vs baseline: 1.0248x; 1.0103x over previous
//
#include <hip/hip_runtime.h>
#include <hip/hip_bf16.h>

#define GEN_EPS 1e-7f

typedef __attribute__((ext_vector_type(8))) short short8;
typedef __attribute__((ext_vector_type(4))) float f32x4;

// ---------------------------------------------------------------------------
// Fused prep: grid-partitioned {wprep(768 blk), count, ln_relu}.
// ---------------------------------------------------------------------------
__global__ void prep_all(
    const float* __restrict__ eW1, const float* __restrict__ eW2,
    const float* __restrict__ nW1, const float* __restrict__ nW2,
    short* __restrict__ eW1P, short* __restrict__ eW2P, short* __restrict__ nW1P,
    short* __restrict__ nW2P,
    const int* __restrict__ e_dst, const int* __restrict__ v_dst,
    int* __restrict__ ce, int* __restrict__ cn, int LE, int En, int nCNT,
    const float* __restrict__ ex, const float* __restrict__ vx,
    const float* __restrict__ eg, const float* __restrict__ eb,
    const float* __restrict__ ng, const float* __restrict__ nb_,
    __hip_bfloat16* __restrict__ he, __hip_bfloat16* __restrict__ hn, int E, int N) {
  int b = blockIdx.x;
  int tid = threadIdx.x;

  if (b < 768) {  // ---- wprep role ----
    const float* W;
    short* WP;
    int R, Cc, c;
    if (b < 256) {
      W = eW1; WP = eW1P; R = 128; Cc = 256; c = b;
    } else if (b < 384) {
      W = eW2; WP = eW2P; R = 256; Cc = 128; c = b - 256;
    } else if (b < 640) {
      W = nW1; WP = nW1P; R = 128; Cc = 256; c = b - 384;
    } else {
      W = nW2; WP = nW2P; R = 256; Cc = 128; c = b - 640;
    }
    size_t tbase = (size_t)(c >> 4) * (size_t)(16 * R);
    int rsub = c & 15;
    for (int k = tid; k < R; k += blockDim.x) {
      __hip_bfloat16 bv = __float2bfloat16(W[(size_t)k * Cc + c]);
      int kk = k & 31;
      WP[tbase + (size_t)(k >> 5) * 512 + (kk >> 3) * 128 + rsub * 8 + (kk & 7)] =
          *(short*)&bv;
    }
    return;
  }
  b -= 768;

  if (b < nCNT) {  // ---- count role ----
    int i = b * 256 + tid;
    if (i < LE)
      atomicAdd(&ce[e_dst[i]], 1);
    else if (i < LE + En)
      atomicAdd(&cn[v_dst[i - LE]], 1);
    return;
  }
  b -= nCNT;

  // ---- ln_relu role: 2 rows per wave, float4 per lane ----
  int l32 = tid & 31;
  int rr = b * 8 + ((tid & 255) >> 5);
  const float* x;
  const float* g;
  const float* bb;
  __hip_bfloat16* h;
  int r;
  if (rr < E) {
    x = ex; g = eg; bb = eb; h = he; r = rr;
  } else if (rr < E + N) {
    x = vx; g = ng; bb = nb_; h = hn; r = rr - E;
  } else {
    return;
  }
  float4 v = ((const float4*)(x + (size_t)r * 128))[l32];
  float s = v.x + v.y + v.z + v.w;
#pragma unroll
  for (int o = 16; o; o >>= 1) s += __shfl_xor(s, o);
  float m = s * (1.0f / 128.0f);
  float d0 = v.x - m, d1 = v.y - m, d2 = v.z - m, d3 = v.w - m;
  float q = d0 * d0 + d1 * d1 + d2 * d2 + d3 * d3;
#pragma unroll
  for (int o = 16; o; o >>= 1) q += __shfl_xor(q, o);
  float rstd = rsqrtf(q * (1.0f / 128.0f) + 1e-5f);
  float4 gv = ((const float4*)g)[l32];
  float4 bv = ((const float4*)bb)[l32];
  float2 h01, h23;
  h01.x = fmaxf(fmaf(d0 * rstd, gv.x, bv.x), 0.0f);
  h01.y = fmaxf(fmaf(d1 * rstd, gv.y, bv.y), 0.0f);
  h23.x = fmaxf(fmaf(d2 * rstd, gv.z, bv.z), 0.0f);
  h23.y = fmaxf(fmaf(d3 * rstd, gv.w, bv.w), 0.0f);
  __hip_bfloat162 p0 = __float22bfloat162_rn(h01);
  __hip_bfloat162 p1 = __float22bfloat162_rn(h23);
  uint2 u;
  u.x = *(uint*)&p0;
  u.y = *(uint*)&p1;
  ((uint2*)(h + (size_t)r * 128))[l32] = u;
}

// ---------------------------------------------------------------------------
// Single-pass exclusive scan (decoupled lookback), both graphs in one launch.
// ---------------------------------------------------------------------------
__global__ void scan_fused(const int* __restrict__ ce, const int* __restrict__ cn,
                           unsigned long long* __restrict__ part,
                           int* __restrict__ off_e, int* __restrict__ off_n,
                           int* __restrict__ cur_e, int* __restrict__ cur_n,
                           int nbE, int E, int N, int LE, int En) {
  __shared__ int sm[256];
  __shared__ int smPrev;
  int b = blockIdx.x;
  const int* counts;
  int M, nnz, bb;
  int* off;
  int* cursor;
  unsigned long long* pr;
  if (b < nbE) {
    counts = ce; M = E; nnz = LE; bb = b; off = off_e; cursor = cur_e; pr = part;
  } else {
    counts = cn; M = N; nnz = En; bb = b - nbE; off = off_n; cursor = cur_n;
    pr = part + 512;
  }
  int t = threadIdx.x;
  int base = bb * 1024 + t * 4;
  int c[4];
  int s = 0;
#pragma unroll
  for (int i = 0; i < 4; i++) {
    int idx = base + i;
    c[i] = (idx < M) ? counts[idx] : 0;
    s += c[i];
  }
  sm[t] = s;
  __syncthreads();
  for (int o = 1; o < 256; o <<= 1) {
    int v = (t >= o) ? sm[t - o] : 0;
    __syncthreads();
    sm[t] += v;
    __syncthreads();
  }
  int total = sm[255];
  if (t == 0) {
    int prev = 0;
    if (bb == 0) {
      atomicExch(&pr[0], (2ULL << 32) | (unsigned long long)(unsigned)total);
    } else {
      atomicExch(&pr[bb], (1ULL << 32) | (unsigned long long)(unsigned)total);
      int j = bb - 1;
      while (true) {
        unsigned long long v;
        do {
          v = atomicAdd(&pr[j], 0ULL);
        } while ((v >> 32) == 0ULL);
        prev += (int)(v & 0xffffffffULL);
        if ((v >> 32) == 2ULL) break;
        j--;
      }
      atomicExch(&pr[bb], (2ULL << 32) | (unsigned long long)(unsigned)(prev + total));
    }
    smPrev = prev;
  }
  __syncthreads();
  int p = smPrev + sm[t] - s;
#pragma unroll
  for (int i = 0; i < 4; i++) {
    int idx = base + i;
    if (idx < M) {
      off[idx] = p;
      cursor[idx] = p;
      p += c[i];
    }
  }
  if (bb == 0 && t == 0) off[M] = nnz;
}

// ---------------------------------------------------------------------------
// Fill: edge graph -> csrs_e (src only); node graph -> interleaved int2.
// ---------------------------------------------------------------------------
__global__ void fill_all(const int* __restrict__ e_src, const int* __restrict__ e_dst,
                         const int* __restrict__ v_src, const int* __restrict__ v_dst,
                         int* __restrict__ cur_e, int* __restrict__ cur_n,
                         int* __restrict__ csrs_e, int2* __restrict__ csrn2,
                         int LE, int En) {
  int i = blockIdx.x * blockDim.x + threadIdx.x;
  if (i < LE) {
    int p = atomicAdd(&cur_e[e_dst[i]], 1);
    csrs_e[p] = e_src[i];
  } else if (i < LE + En) {
    int j = i - LE;
    int p = atomicAdd(&cur_n[v_dst[j]], 1);
    int2 st;
    st.x = v_src[j];
    st.y = j;
    csrn2[p] = st;
  }
}

// ---------------------------------------------------------------------------
// Softmax aggregation: one wave = 2 rows (32 lanes/row, 4 channels/lane via
// 8B gathers), 4-way edge-parallel unroll.
// ---------------------------------------------------------------------------
template <bool HAS_EATTR>
__global__ __launch_bounds__(256) void aggregate_kernel(
    const __hip_bfloat16* __restrict__ h, const int* __restrict__ off,
    const int* __restrict__ csr_src, const int2* __restrict__ csr2,
    const ushort* __restrict__ eattr, const float* __restrict__ tptr,
    uint* __restrict__ yP, int M) {
  int l32 = threadIdx.x & 31;
  int r = blockIdx.x * 8 + (threadIdx.x >> 5);
  if (r >= M) return;
  const float t = tptr[0];
  int e0 = off[r], e1 = off[r + 1];
  float d0 = 0, d1 = 0, d2 = 0, d3 = 0, a0 = 0, a1 = 0, a2 = 0, a3 = 0;
  for (int e = e0; e < e1; e += 4) {
    int n = e1 - e;
    uint2 mraw[4];
    int ids[4];
#pragma unroll
    for (int u = 0; u < 4; u++) {
      int ee = (u < n) ? e + u : e;
      int s;
      if (HAS_EATTR) {
        int2 se = csr2[ee];
        s = se.x;
        ids[u] = se.y;
      } else {
        s = csr_src[ee];
      }
      mraw[u] = ((const uint2*)(h + (size_t)s * 128))[l32];
    }
#pragma unroll
    for (int u = 0; u < 4; u++) {
      float2 lo = __bfloat1622float2(*(__hip_bfloat162*)&mraw[u].x);
      float2 hi2 = __bfloat1622float2(*(__hip_bfloat162*)&mraw[u].y);
      if (HAS_EATTR) {
        uint2 er = ((const uint2*)(eattr + (size_t)ids[u] * 128))[l32];
        float2 el = __bfloat1622float2(*(__hip_bfloat162*)&er.x);
        float2 eh = __bfloat1622float2(*(__hip_bfloat162*)&er.y);
        lo.x += el.x;
        lo.y += el.y;
        hi2.x += eh.x;
        hi2.y += eh.y;
      }
      float w = (u < n) ? 1.0f : 0.0f;
      float m0 = fmaxf(lo.x, 0.0f) + GEN_EPS;
      float m1 = fmaxf(lo.y, 0.0f) + GEN_EPS;
      float m2 = fmaxf(hi2.x, 0.0f) + GEN_EPS;
      float m3 = fmaxf(hi2.y, 0.0f) + GEN_EPS;
      float al0 = __expf(m0 * t) * w, al1 = __expf(m1 * t) * w;
      float al2 = __expf(m2 * t) * w, al3 = __expf(m3 * t) * w;
      d0 += al0;
      d1 += al1;
      d2 += al2;
      d3 += al3;
      a0 = fmaf(al0, m0, a0);
      a1 = fmaf(al1, m1, a1);
      a2 = fmaf(al2, m2, a2);
      a3 = fmaf(al3, m3, a3);
    }
  }
  uint2 hraw = ((const uint2*)(h + (size_t)r * 128))[l32];
  float2 hlo = __bfloat1622float2(*(__hip_bfloat162*)&hraw.x);
  float2 hhi = __bfloat1622float2(*(__hip_bfloat162*)&hraw.y);
  bool has = e1 > e0;
  float2 y01, y23;
  y01.x = (has ? a0 / d0 : 0.0f) + hlo.x;
  y01.y = (has ? a1 / d1 : 0.0f) + hlo.y;
  y23.x = (has ? a2 / d2 : 0.0f) + hhi.x;
  y23.y = (has ? a3 / d3 : 0.0f) + hhi.y;
  __hip_bfloat162 pb0 = __float22bfloat162_rn(y01);
  __hip_bfloat162 pb1 = __float22bfloat162_rn(y23);
  int base = (r >> 4) * 1024 + (r & 15) * 16;
  int c0 = 2 * l32, c1 = 2 * l32 + 1;
  yP[base + (c0 >> 4) * 256 + (c0 & 15)] = *(uint*)&pb0;
  yP[base + (c1 >> 4) * 256 + (c1 & 15)] = *(uint*)&pb1;
}

// ---------------------------------------------------------------------------
// Persistent MLP (512 threads, 8 waves, 2 waves/SIMD).  W1+W2 in LDS.
// fp32 out written with NON-TEMPORAL stores (write-once stream, never re-read
// on-device) -> no L2 write-allocate, preserving L2 for yP/x read streams.
// ---------------------------------------------------------------------------
template <bool WRITE_BF16>
__global__ __launch_bounds__(512, 2) void mlp_kernel(
    const float* __restrict__ x, const short* yP, const short* __restrict__ W1P,
    const float* __restrict__ b1, const float* __restrict__ lng,
    const float* __restrict__ lnb, const short* __restrict__ W2P,
    const float* __restrict__ b2, float* __restrict__ out, ushort* out16,
    int ntiles, int stride, int M) {
  __shared__ short W1s[128 * 256];
  __shared__ short W2s[256 * 128];
  __shared__ short scr[8][2][16 * 34];

  const int tid = threadIdx.x, lane = tid & 63, wv = tid >> 6;
  const int rA = lane & 15, hi = lane >> 4;
  const int kA = hi * 8, jrow = hi * 4;
  const int foW = lane * 8;
  const int foA = rA * 32 + kA;

  {
    const short8* g1 = (const short8*)W1P;
    short8* l1 = (short8*)W1s;
#pragma unroll
    for (int i = 0; i < 8; i++) l1[i * 512 + tid] = g1[i * 512 + tid];
    const short8* g2 = (const short8*)W2P;
    short8* l2 = (short8*)W2s;
#pragma unroll
    for (int i = 0; i < 8; i++) l2[i * 512 + tid] = g2[i * 512 + tid];
  }

  float b1v[16], lngv[16], lnbv[16], b2v[8];
#pragma unroll
  for (int ct = 0; ct < 16; ct++) {
    int col = ct * 16 + rA;
    b1v[ct] = b1[col];
    lngv[ct] = lng[col];
    lnbv[ct] = lnb[col];
  }
#pragma unroll
  for (int ct = 0; ct < 8; ct++) b2v[ct] = b2[ct * 16 + rA];

  __syncthreads();

  int t = blockIdx.x * 8 + wv;
  short8 yA0, yA1, yA2, yA3;
  if (t < ntiles) {
    const short* yb = yP + (size_t)t * 2048 + foA;
    yA0 = *(const short8*)(yb);
    yA1 = *(const short8*)(yb + 512);
    yA2 = *(const short8*)(yb + 1024);
    yA3 = *(const short8*)(yb + 1536);
  }

  for (; t < ntiles; t += stride) {
    const int row0 = t * 16;

    f32x4 C1[16];
#pragma unroll
    for (int i = 0; i < 16; i++) C1[i] = (f32x4)0.0f;
#pragma unroll
    for (int kc = 0; kc < 4; kc++) {
      short8 a = (kc == 0) ? yA0 : (kc == 1) ? yA1 : (kc == 2) ? yA2 : yA3;
#pragma unroll
      for (int ct = 0; ct < 16; ct++) {
        short8 B = *(const short8*)&W1s[(ct * 4 + kc) * 512 + foW];
        C1[ct] = __builtin_amdgcn_mfma_f32_16x16x32_bf16(a, B, C1[ct], 0, 0, 0);
      }
    }

    {
      int tn = t + stride;
      int tc = (tn < ntiles) ? tn : t;
      const short* yb = yP + (size_t)tc * 2048 + foA;
      yA0 = *(const short8*)(yb);
      yA1 = *(const short8*)(yb + 512);
      yA2 = *(const short8*)(yb + 1024);
      yA3 = *(const short8*)(yb + 1536);
    }

    float xv[32];
#pragma unroll
    for (int ct = 0; ct < 8; ct++)
#pragma unroll
      for (int j = 0; j < 4; j++) {
        int row = row0 + jrow + j;
        int rr = (row < M) ? row : (M - 1);
        xv[ct * 4 + j] = x[(size_t)rr * 128 + ct * 16 + rA];
      }

#pragma unroll
    for (int ct = 0; ct < 16; ct++)
#pragma unroll
      for (int j = 0; j < 4; j++) C1[ct][j] += b1v[ct];

    float mean[4], rstd[4];
#pragma unroll
    for (int j = 0; j < 4; j++) {
      float p = 0.0f, q = 0.0f;
#pragma unroll
      for (int ct = 0; ct < 16; ct++) {
        p += C1[ct][j];
        q = fmaf(C1[ct][j], C1[ct][j], q);
      }
#pragma unroll
      for (int o = 1; o < 16; o <<= 1) {
        p += __shfl_xor(p, o);
        q += __shfl_xor(q, o);
      }
      float m = p * (1.0f / 256.0f);
      mean[j] = m;
      rstd[j] = rsqrtf(q * (1.0f / 256.0f) - m * m + 1e-5f);
    }

    f32x4 C2[8];
#pragma unroll
    for (int i = 0; i < 8; i++) C2[i] = (f32x4)0.0f;
#pragma unroll
    for (int kc = 0; kc < 8; kc++) {
      short* s = &scr[wv][kc & 1][0];
#pragma unroll
      for (int ct2 = 0; ct2 < 2; ct2++) {
        int ctg = kc * 2 + ct2;
#pragma unroll
        for (int j = 0; j < 4; j++) {
          float v =
              fmaxf(fmaf((C1[ctg][j] - mean[j]) * rstd[j], lngv[ctg], lnbv[ctg]), 0.0f);
          __hip_bfloat16 bv = __float2bfloat16(v);
          s[(jrow + j) * 34 + ct2 * 16 + rA] = *(short*)&bv;
        }
      }
      asm volatile("s_waitcnt lgkmcnt(0)" ::: "memory");
      __builtin_amdgcn_sched_barrier(0);
      short8 a = *(const short8*)&s[rA * 34 + kA];
#pragma unroll
      for (int ct = 0; ct < 8; ct++) {
        short8 B = *(const short8*)&W2s[(ct * 8 + kc) * 512 + foW];
        C2[ct] = __builtin_amdgcn_mfma_f32_16x16x32_bf16(a, B, C2[ct], 0, 0, 0);
      }
    }

#pragma unroll
    for (int ct = 0; ct < 8; ct++) {
#pragma unroll
      for (int j = 0; j < 4; j++) {
        int row = row0 + jrow + j;
        if (row < M) {
          size_t idx = (size_t)row * 128 + ct * 16 + rA;
          float o = C2[ct][j] + b2v[ct] + xv[ct * 4 + j];
          __builtin_nontemporal_store(o, &out[idx]);
          if (WRITE_BF16) {
            __hip_bfloat16 bo = __float2bfloat16(o);
            out16[idx] = *(ushort*)&bo;
          }
        }
      }
    }
  }
}

// ---------------------------------------------------------------------------
extern "C" void kernel_launch(void* const* d_in, const int* in_sizes, int n_in,
                              void* d_out, int out_size, void* d_ws, size_t ws_size,
                              hipStream_t stream) {
  const int C = 128;
  const float* v_x = (const float*)d_in[0];
  const float* e_x = (const float*)d_in[1];
  const int* v_ei = (const int*)d_in[2];
  const int* e_ei = (const int*)d_in[3];
  const int N = in_sizes[0] / C;
  const int E = in_sizes[1] / C;
  const int LE = in_sizes[3] / 2;

  const float* ep[9];
  const float* np_[9];
  for (int i = 0; i < 9; i++) ep[i] = (const float*)d_in[4 + i];
  for (int i = 0; i < 9; i++) np_[i] = (const float*)d_in[13 + i];

  float* v_out = (float*)d_out;
  float* e_out = (float*)d_out + (size_t)N * C;

  char* wsp = (char*)d_ws;
  size_t o = 0;
  auto carve = [&](size_t bytes) {
    void* p = wsp + o;
    o += (bytes + 255) & ~(size_t)255;
    return p;
  };
  short* yPe = (short*)carve((size_t)E * C * 2);  // edge packed y; later bf16 e_out
  short* yPn = (short*)carve((size_t)N * C * 2);  // node packed y
  int* counts = (int*)carve((size_t)(E + N) * 4);
  unsigned long long* part = (unsigned long long*)carve(1024 * 8);  // after counts
  int* off_e = (int*)carve(((size_t)E + 1) * 4);
  int* off_n = (int*)carve(((size_t)N + 1) * 4);
  int* cur_e = (int*)carve((size_t)E * 4);
  int* cur_n = (int*)carve((size_t)N * 4);
  int* csrs_e = (int*)carve((size_t)LE * 4);
  int2* csrn2 = (int2*)carve((size_t)E * 8);
  short* eW1P = (short*)carve((size_t)256 * 128 * 2);
  short* eW2P = (short*)carve((size_t)128 * 256 * 2);
  short* nW1P = (short*)carve((size_t)256 * 128 * 2);
  short* nW2P = (short*)carve((size_t)128 * 256 * 2);
  (void)ws_size;
  (void)n_in;
  (void)out_size;

  int* counts_e = counts;
  int* counts_n = counts + E;
  __hip_bfloat16* h_e = (__hip_bfloat16*)e_out;  // dead before mlp_e writes
  __hip_bfloat16* h_n = (__hip_bfloat16*)v_out;  // dead before mlp_n writes

  // ---- fused prep: wprep + count + ln_relu; memset covers counts AND part ----
  size_t counts_pad = (((size_t)(E + N) * 4) + 255) & ~(size_t)255;
  hipMemsetAsync(counts, 0, counts_pad + 1024 * 8, stream);
  int nCNT = (LE + E + 255) / 256;
  int nLN = (E + N + 7) / 8;
  prep_all<<<768 + nCNT + nLN, 256, 0, stream>>>(
      ep[3], ep[7], np_[3], np_[7], eW1P, eW2P, nW1P, nW2P, e_ei + LE, v_ei + E,
      counts_e, counts_n, LE, E, nCNT, e_x, v_x, ep[0], ep[1], np_[0], np_[1], h_e, h_n,
      E, N);
  int nbE = (E + 1023) / 1024, nbN = (N + 1023) / 1024;
  scan_fused<<<nbE + nbN, 256, 0, stream>>>(counts_e, counts_n, part, off_e, off_n,
                                            cur_e, cur_n, nbE, E, N, LE, E);
  fill_all<<<(LE + E + 255) / 256, 256, 0, stream>>>(e_ei, e_ei + LE, v_ei, v_ei + E,
                                                     cur_e, cur_n, csrs_e, csrn2, LE, E);

  // ---- edge layer ----
  aggregate_kernel<false><<<(E + 7) / 8, 256, 0, stream>>>(
      h_e, off_e, csrs_e, nullptr, nullptr, ep[2], (uint*)yPe, E);
  {
    int ntiles = (E + 15) / 16;
    int gblocks = (ntiles + 7) / 8;
    if (gblocks > 256) gblocks = 256;
    int stride = gblocks * 8;
    mlp_kernel<true><<<gblocks, 512, 0, stream>>>(e_x, yPe, eW1P, ep[4], ep[5], ep[6],
                                                  eW2P, ep[8], e_out, (ushort*)yPe,
                                                  ntiles, stride, E);
  }

  // ---- node layer ----
  aggregate_kernel<true><<<(N + 7) / 8, 256, 0, stream>>>(
      h_n, off_n, nullptr, csrn2, (const ushort*)yPe, np_[2], (uint*)yPn, N);
  {
    int ntiles = (N + 15) / 16;
    int gblocks = (ntiles + 7) / 8;
    if (gblocks > 256) gblocks = 256;
    int stride = gblocks * 8;
    mlp_kernel<false><<<gblocks, 512, 0, stream>>>(v_x, yPn, nW1P, np_[4], np_[5], np_[6],
                                                   nW2P, np_[8], v_out, nullptr, ntiles,
                                                   stride, N);
  }
}